// Round 3
// baseline (4423.273 us; speedup 1.0000x reference)
//
#include <hip/hip_runtime.h>
#include <stdint.h>

#define N      12288              // 96*128 descriptors
#define CH     512                // channels
#define NTILE  96                 // N/128
#define NS     8                  // j-slices (grid.y)
#define JT_PER_S 12               // j-tiles per slice

typedef _Float16 f16x8 __attribute__((ext_vector_type(8)));
typedef float    f32x4 __attribute__((ext_vector_type(4)));

struct Top2 { float v0, v1; int i0, i1; };

// ---- module-scope device scratch (graph-capture safe, rewritten every launch)
__device__ float g_invA[N];
__device__ float g_invB[N];
// split-fp16 transposed operands: [d][16 k-groups][32 hi | 32 lo] halfs (2 KB/row)
__device__ unsigned short g_AT[(size_t)N * 1024];
__device__ unsigned short g_BT[(size_t)N * 1024];
__device__ Top2  g_rpart[NS][N];
__device__ Top2  g_cpart[NTILE][N];
__device__ int   g_nn12[N];
__device__ float g_r12[N];
__device__ float g_sim0[N];
__device__ int   g_nn21[N];
__device__ float g_r21[N];

// insert candidate (v, idx) into running top-2; ties -> lower index (lax.top_k)
__device__ __forceinline__ void t2_ins(float v, int idx,
                                       float& v0, int& i0, float& v1, int& i1) {
  bool beats0 = (v > v0) || (v == v0 && idx < i0);
  bool beats1 = (v > v1) || (v == v1 && idx < i1);
  if (beats0) { v1 = v0; i1 = i0; v0 = v; i0 = idx; }
  else if (beats1) { v1 = v; i1 = idx; }
}

__device__ __forceinline__ float bf16_quant(float f) {
  unsigned int u = __float_as_uint(f);
  unsigned int r = 0x7fffu + ((u >> 16) & 1u);
  unsigned int q = ((u + r) >> 16) << 16;
  return __uint_as_float(q);
}

// ---------------- kernel 1: transpose + split-fp16 + inverse norms ----------------
// grid (192, 2): 64 descriptors per block; y=0 -> A, y=1 -> B.
// x' = 1024*x (avoids fp16 subnormals); hi=fp16(x'), lo=fp16(x'-hi).
// norms accumulate x'^2 so invA = 1/sqrt(sum) already folds the 2^-20.
__global__ __launch_bounds__(256)
void prep_kernel(const float* __restrict__ A, const float* __restrict__ B) {
  const int d0 = blockIdx.x * 64;
  const float* src = blockIdx.y ? B : A;
  unsigned short* dst = blockIdx.y ? g_BT : g_AT;
  float* inv = blockIdx.y ? g_invB : g_invA;

  __shared__ float Ls[32][68];            // fp32 in-tile (68: 16B-aligned rows)
  __shared__ unsigned short Os[64][64];   // packed out-tile [d][32 hi|32 lo]
  __shared__ float Ps[4][64];             // norm partials

  const int t = threadIdx.x;
  const int a = t >> 6, dl = t & 63;
  float sum = 0.f;

  for (int g = 0; g < 16; ++g) {
    __syncthreads();
    {   // load [32 ch][64 d] fp32 tile, coalesced
      const int c = t >> 3, dc = (t & 7) * 8;
      const float* p = src + (size_t)(g * 32 + c) * N + d0 + dc;
      float4 v0 = *reinterpret_cast<const float4*>(p);
      float4 v1 = *reinterpret_cast<const float4*>(p + 4);
      *reinterpret_cast<float4*>(&Ls[c][dc])     = v0;
      *reinterpret_cast<float4*>(&Ls[c][dc + 4]) = v1;
    }
    __syncthreads();
    {   // split 8 channels per thread, pack into Os
      _Float16 hv[8] __attribute__((aligned(16)));
      _Float16 lv[8] __attribute__((aligned(16)));
#pragma unroll
      for (int j = 0; j < 8; ++j) {
        float v = Ls[a * 8 + j][dl] * 1024.0f;
        sum += v * v;
        _Float16 h = (_Float16)v;
        float rr = v - (float)h;          // exact in fp32
        hv[j] = h;
        lv[j] = (_Float16)rr;
      }
      *reinterpret_cast<uint4*>(&Os[dl][a * 8])      = *reinterpret_cast<const uint4*>(hv);
      *reinterpret_cast<uint4*>(&Os[dl][32 + a * 8]) = *reinterpret_cast<const uint4*>(lv);
    }
    __syncthreads();
    {   // store out-tile: 128 B contiguous per descriptor row
#pragma unroll
      for (int p2 = 0; p2 < 2; ++p2) {
        const int d = p2 * 32 + (t >> 3), ch = t & 7;
        *reinterpret_cast<uint4*>((char*)(dst + (size_t)(d0 + d) * 1024) + g * 128 + ch * 16)
            = *reinterpret_cast<const uint4*>(&Os[d][ch * 8]);
      }
    }
  }
  Ps[a][dl] = sum;
  __syncthreads();
  if (t < 64) {
    float tot = Ps[0][t] + Ps[1][t] + Ps[2][t] + Ps[3][t];
    inv[d0 + t] = 1.0f / sqrtf(tot);
  }
}

// ---------------- kernel 2: MFMA GEMM + fused dual top-2 ----------------
// grid (96, 8). 128x128 tile, 4 waves, each wave a 64x64 quadrant of 4x4
// 16x16 fragments. Per K-step (32 ch): stage [128][32hi|32lo] fp16 tiles
// (144 B padded rows), 3-term MFMA: acc += Ah*Bh + Ah*Bl + Al*Bh.
// Next-group global loads prefetch under MFMA.
// __launch_bounds__(256, 2): R2's (256,3) capped unified VGPR+AGPR at 168
// -> scratch spill (WRITE_SIZE 3.9 GB, 18x slowdown). Cap 256 fits ~190 live.
__global__ __launch_bounds__(256, 2)
void sim_top2_mfma() {
  __shared__ unsigned short As[128][72];   // 144 B pitch, data in first 128 B
  __shared__ unsigned short Bs[128][72];
  __shared__ Top2 rowW[2][128];            // per-wc row partials (persistent)
  __shared__ Top2 colW[2][128];            // per-wr col partials (per j-tile)
  __shared__ float iaS[128];
  __shared__ float ibS[128];

  const int itile = blockIdx.x, slice = blockIdx.y;
  const int i0 = itile * 128;
  const int tid = threadIdx.x;
  const int wave = tid >> 6, lane = tid & 63;
  const int wr = wave >> 1, wc = wave & 1;
  const int fr = lane & 15, kq = lane >> 4;

  if (tid < 128) {
    iaS[tid] = g_invA[i0 + tid];
    Top2 z; z.v0 = -1e30f; z.v1 = -1e30f; z.i0 = 0x7fffffff; z.i1 = 0x7fffffff;
    rowW[0][tid] = z; rowW[1][tid] = z;
  }

  const int srow = wave * 8 + (lane >> 3);   // 0..31, +it*32 covers 128 rows
  const int soff = (lane & 7) * 16;          // byte chunk within 128-B row
  const char* gA = (const char*)g_AT + (size_t)(i0 + srow) * 2048 + soff;

  for (int jt = slice * JT_PER_S; jt < slice * JT_PER_S + JT_PER_S; ++jt) {
    const int j0 = jt * 128;
    if (tid < 128) ibS[tid] = g_invB[j0 + tid];

    f32x4 acc[4][4];
#pragma unroll
    for (int mi = 0; mi < 4; ++mi)
#pragma unroll
      for (int ni = 0; ni < 4; ++ni)
#pragma unroll
        for (int q = 0; q < 4; ++q) acc[mi][ni][q] = 0.f;

    const char* gB = (const char*)g_BT + (size_t)(j0 + srow) * 2048 + soff;

    uint4 ga[4], gb[4];
#pragma unroll
    for (int it = 0; it < 4; ++it) {
      ga[it] = *reinterpret_cast<const uint4*>(gA + (size_t)it * 32 * 2048);
      gb[it] = *reinterpret_cast<const uint4*>(gB + (size_t)it * 32 * 2048);
    }

    for (int g = 0; g < 16; ++g) {
      __syncthreads();                       // previous tile fully consumed
#pragma unroll
      for (int it = 0; it < 4; ++it) {
        *reinterpret_cast<uint4*>((char*)&As[srow + it * 32][0] + soff) = ga[it];
        *reinterpret_cast<uint4*>((char*)&Bs[srow + it * 32][0] + soff) = gb[it];
      }
      __syncthreads();                       // tile g visible
      if (g < 15) {                          // prefetch g+1 under the MFMA block
#pragma unroll
        for (int it = 0; it < 4; ++it) {
          ga[it] = *reinterpret_cast<const uint4*>(gA + (size_t)it * 32 * 2048 + (size_t)(g + 1) * 128);
          gb[it] = *reinterpret_cast<const uint4*>(gB + (size_t)it * 32 * 2048 + (size_t)(g + 1) * 128);
        }
      }
      f16x8 ah[4], al[4];
#pragma unroll
      for (int mi = 0; mi < 4; ++mi) {
        const unsigned short* p = &As[wr * 64 + mi * 16 + fr][kq * 8];
        ah[mi] = *reinterpret_cast<const f16x8*>(p);
        al[mi] = *reinterpret_cast<const f16x8*>(p + 32);
      }
#pragma unroll
      for (int ni = 0; ni < 4; ++ni) {
        const unsigned short* q = &Bs[wc * 64 + ni * 16 + fr][kq * 8];
        f16x8 bh = *reinterpret_cast<const f16x8*>(q);
        f16x8 bl = *reinterpret_cast<const f16x8*>(q + 32);
#pragma unroll
        for (int mi = 0; mi < 4; ++mi) {
          acc[mi][ni] = __builtin_amdgcn_mfma_f32_16x16x32_f16(ah[mi], bh, acc[mi][ni], 0, 0, 0);
          acc[mi][ni] = __builtin_amdgcn_mfma_f32_16x16x32_f16(ah[mi], bl, acc[mi][ni], 0, 0, 0);
          acc[mi][ni] = __builtin_amdgcn_mfma_f32_16x16x32_f16(al[mi], bh, acc[mi][ni], 0, 0, 0);
        }
      }
    }

    // ---- epilogue: scale to cosine sims (C layout: col=fr, row=kq*4+r) ----
    float ib[4];
#pragma unroll
    for (int ni = 0; ni < 4; ++ni) ib[ni] = ibS[wc * 64 + ni * 16 + fr];
#pragma unroll
    for (int mi = 0; mi < 4; ++mi)
#pragma unroll
      for (int r = 0; r < 4; ++r) {
        const float iar = iaS[wr * 64 + mi * 16 + kq * 4 + r];
#pragma unroll
        for (int ni = 0; ni < 4; ++ni)
          acc[mi][ni][r] *= iar * ib[ni];
      }

    // ---- row top-2 (reduce over cols: lanes sharing kq, then ni) ----
#pragma unroll
    for (int mi = 0; mi < 4; ++mi) {
#pragma unroll
      for (int r = 0; r < 4; ++r) {
        const int row = wr * 64 + mi * 16 + kq * 4 + r;
        float v0 = -1e30f, v1 = -1e30f; int id0 = 0x7fffffff, id1 = 0x7fffffff;
#pragma unroll
        for (int ni = 0; ni < 4; ++ni)
          t2_ins(acc[mi][ni][r], j0 + wc * 64 + ni * 16 + fr, v0, id0, v1, id1);
#pragma unroll
        for (int m = 1; m < 16; m <<= 1) {
          float ov0 = __shfl_xor(v0, m), ov1 = __shfl_xor(v1, m);
          int oi0 = __shfl_xor(id0, m), oi1 = __shfl_xor(id1, m);
          t2_ins(ov0, oi0, v0, id0, v1, id1);
          t2_ins(ov1, oi1, v0, id0, v1, id1);
        }
        if (fr == 0) {                       // unique (wave, kq, mi, r) owner
          Top2 tT = rowW[wc][row];
          t2_ins(v0, id0, tT.v0, tT.i0, tT.v1, tT.i1);
          t2_ins(v1, id1, tT.v0, tT.i0, tT.v1, tT.i1);
          rowW[wc][row] = tT;
        }
      }
    }

    // ---- col top-2 (reduce 16 in-thread rows, then across kq groups) ----
#pragma unroll
    for (int ni = 0; ni < 4; ++ni) {
      float v0 = -1e30f, v1 = -1e30f; int id0 = 0x7fffffff, id1 = 0x7fffffff;
#pragma unroll
      for (int mi = 0; mi < 4; ++mi)
#pragma unroll
        for (int r = 0; r < 4; ++r)
          t2_ins(acc[mi][ni][r], i0 + wr * 64 + mi * 16 + kq * 4 + r, v0, id0, v1, id1);
#pragma unroll
      for (int m = 16; m < 64; m <<= 1) {
        float ov0 = __shfl_xor(v0, m), ov1 = __shfl_xor(v1, m);
        int oi0 = __shfl_xor(id0, m), oi1 = __shfl_xor(id1, m);
        t2_ins(ov0, oi0, v0, id0, v1, id1);
        t2_ins(ov1, oi1, v0, id0, v1, id1);
      }
      if (kq == 0) {
        Top2 tT; tT.v0 = v0; tT.v1 = v1; tT.i0 = id0; tT.i1 = id1;
        colW[wr][wc * 64 + ni * 16 + fr] = tT;
      }
    }
    __syncthreads();
    if (tid < 128) {
      Top2 tT = colW[0][tid];
      Top2 o  = colW[1][tid];
      t2_ins(o.v0, o.i0, tT.v0, tT.i0, tT.v1, tT.i1);
      t2_ins(o.v1, o.i1, tT.v0, tT.i0, tT.v1, tT.i1);
      g_cpart[itile][j0 + tid] = tT;
    }
  }

  __syncthreads();
  if (tid < 128) {
    Top2 tT = rowW[0][tid];
    Top2 o  = rowW[1][tid];
    t2_ins(o.v0, o.i0, tT.v0, tT.i0, tT.v1, tT.i1);
    t2_ins(o.v1, o.i1, tT.v0, tT.i0, tT.v1, tT.i1);
    g_rpart[slice][i0 + tid] = tT;
  }
}

// ---------------- kernel 3: merge partials ----------------
__global__ void merge_kernel() {
  int i = blockIdx.x * 256 + threadIdx.x;
  if (i >= N) return;
  {
    float v0 = -1e30f, v1 = -1e30f; int id0 = 0x7fffffff, id1 = 0x7fffffff;
#pragma unroll
    for (int s = 0; s < NS; ++s) {
      Top2 p = g_rpart[s][i];
      t2_ins(p.v0, p.i0, v0, id0, v1, id1);
      t2_ins(p.v1, p.i1, v0, id0, v1, id1);
    }
    float d0 = 2.f - 2.f * v0, d1 = 2.f - 2.f * v1;
    g_nn12[i] = id0; g_r12[i] = d0 / (d1 + 1e-8f); g_sim0[i] = v0;
  }
  {
    float v0 = -1e30f, v1 = -1e30f; int id0 = 0x7fffffff, id1 = 0x7fffffff;
    for (int it = 0; it < NTILE; ++it) {
      Top2 p = g_cpart[it][i];
      t2_ins(p.v0, p.i0, v0, id0, v1, id1);
      t2_ins(p.v1, p.i1, v0, id0, v1, id1);
    }
    float d0 = 2.f - 2.f * v0, d1 = 2.f - 2.f * v1;
    g_nn21[i] = id0; g_r21[i] = d0 / (d1 + 1e-8f);
  }
}

// ---------------- kernel 4: mutual-NN + ratio mask, outputs ----------------
__global__ void finalize_kernel(float* __restrict__ out) {
  int i = blockIdx.x * 256 + threadIdx.x;
  if (i >= N) return;
  int j = g_nn12[i];
  int jc = j < 0 ? 0 : (j >= N ? N - 1 : j);
  bool mask = (g_nn21[jc] == i) && (g_r12[i] <= 0.95f) && (g_r21[jc] <= 0.95f);
  out[i]         = bf16_quant(mask ? g_sim0[i] : 0.f);
  out[N + i]     = bf16_quant((float)j);
  out[2 * N + i] = mask ? 1.f : 0.f;
}

extern "C" void kernel_launch(void* const* d_in, const int* in_sizes, int n_in,
                              void* d_out, int out_size, void* d_ws, size_t ws_size,
                              hipStream_t stream) {
  const float* A = (const float*)d_in[0];  // fp32, channel-major [CH][N]
  const float* B = (const float*)d_in[1];
  (void)d_ws; (void)ws_size;

  prep_kernel<<<dim3(192, 2), 256, 0, stream>>>(A, B);
  sim_top2_mfma<<<dim3(NTILE, NS), 256, 0, stream>>>();
  merge_kernel<<<dim3((N + 255) / 256), 256, 0, stream>>>();
  finalize_kernel<<<dim3((N + 255) / 256), 256, 0, stream>>>((float*)d_out);
}

// Round 4
// 2333.283 us; speedup vs baseline: 1.8957x; 1.8957x over previous
//
#include <hip/hip_runtime.h>
#include <stdint.h>

#define N      12288              // 96*128 descriptors
#define CH     512                // channels
#define NTILE  96                 // N/128
#define NS     8                  // j-slices (grid.y)
#define JT_PER_S 12               // j-tiles per slice

typedef _Float16 f16x8 __attribute__((ext_vector_type(8)));
typedef float    f32x4 __attribute__((ext_vector_type(4)));

struct Top2 { float v0, v1; int i0, i1; };

// ---- module-scope device scratch (graph-capture safe, rewritten every launch)
__device__ float g_invA[N];
__device__ float g_invB[N];
// split-fp16 transposed operands: [d][16 k-groups][8 chunks of 16B] where the
// chunk order within each 128B row is XOR-swizzled by (d&7): chunk c of the
// LOGICAL [32 hi | 32 lo] layout lives at physical chunk c^(d&7).  This makes
// the linear global_load_lds copy produce a bank-conflict-free LDS layout.
__device__ unsigned short g_AT[(size_t)N * 1024];
__device__ unsigned short g_BT[(size_t)N * 1024];
__device__ Top2  g_rpart[NS][N];
__device__ Top2  g_cpart[NTILE][N];
__device__ int   g_nn12[N];
__device__ float g_r12[N];
__device__ float g_sim0[N];
__device__ int   g_nn21[N];
__device__ float g_r21[N];

// insert candidate (v, idx) into running top-2; ties -> lower index (lax.top_k)
__device__ __forceinline__ void t2_ins(float v, int idx,
                                       float& v0, int& i0, float& v1, int& i1) {
  bool beats0 = (v > v0) || (v == v0 && idx < i0);
  bool beats1 = (v > v1) || (v == v1 && idx < i1);
  if (beats0) { v1 = v0; i1 = i0; v0 = v; i0 = idx; }
  else if (beats1) { v1 = v; i1 = idx; }
}

__device__ __forceinline__ float bf16_quant(float f) {
  unsigned int u = __float_as_uint(f);
  unsigned int r = 0x7fffu + ((u >> 16) & 1u);
  unsigned int q = ((u + r) >> 16) << 16;
  return __uint_as_float(q);
}

// async global->LDS, 16 B per lane; LDS dest = wave-uniform base + lane*16
__device__ __forceinline__ void gload16(const void* g, void* lds) {
  __builtin_amdgcn_global_load_lds((const __attribute__((address_space(1))) void*)g,
                                   (__attribute__((address_space(3))) void*)lds,
                                   16, 0, 0);
}

// ---------------- kernel 1: transpose + split-fp16 + inverse norms ----------------
// grid (192, 2): 64 descriptors per block; y=0 -> A, y=1 -> B.
// x' = 1024*x (avoids fp16 subnormals); hi=fp16(x'), lo=fp16(x'-hi).
// Store with per-row chunk swizzle c -> c^(d&7) (see g_AT comment).
__global__ __launch_bounds__(256)
void prep_kernel(const float* __restrict__ A, const float* __restrict__ B) {
  const int d0 = blockIdx.x * 64;
  const float* src = blockIdx.y ? B : A;
  unsigned short* dst = blockIdx.y ? g_BT : g_AT;
  float* inv = blockIdx.y ? g_invB : g_invA;

  __shared__ float Ls[32][68];            // fp32 in-tile (68: 16B-aligned rows)
  __shared__ unsigned short Os[64][64];   // packed out-tile [d][32 hi|32 lo]
  __shared__ float Ps[4][64];             // norm partials

  const int t = threadIdx.x;
  const int a = t >> 6, dl = t & 63;
  float sum = 0.f;

  for (int g = 0; g < 16; ++g) {
    __syncthreads();
    {   // load [32 ch][64 d] fp32 tile, coalesced
      const int c = t >> 3, dc = (t & 7) * 8;
      const float* p = src + (size_t)(g * 32 + c) * N + d0 + dc;
      float4 v0 = *reinterpret_cast<const float4*>(p);
      float4 v1 = *reinterpret_cast<const float4*>(p + 4);
      *reinterpret_cast<float4*>(&Ls[c][dc])     = v0;
      *reinterpret_cast<float4*>(&Ls[c][dc + 4]) = v1;
    }
    __syncthreads();
    {   // split 8 channels per thread, pack into Os
      _Float16 hv[8] __attribute__((aligned(16)));
      _Float16 lv[8] __attribute__((aligned(16)));
#pragma unroll
      for (int j = 0; j < 8; ++j) {
        float v = Ls[a * 8 + j][dl] * 1024.0f;
        sum += v * v;
        _Float16 h = (_Float16)v;
        float rr = v - (float)h;          // exact in fp32
        hv[j] = h;
        lv[j] = (_Float16)rr;
      }
      *reinterpret_cast<uint4*>(&Os[dl][a * 8])      = *reinterpret_cast<const uint4*>(hv);
      *reinterpret_cast<uint4*>(&Os[dl][32 + a * 8]) = *reinterpret_cast<const uint4*>(lv);
    }
    __syncthreads();
    {   // store out-tile: 128 B per descriptor row, chunks XOR-swizzled
#pragma unroll
      for (int p2 = 0; p2 < 2; ++p2) {
        const int d = p2 * 32 + (t >> 3), ch = t & 7;
        const int sc = ch ^ (d & 7);      // swizzled chunk slot
        *reinterpret_cast<uint4*>((char*)(dst + (size_t)(d0 + d) * 1024) + g * 128 + sc * 16)
            = *reinterpret_cast<const uint4*>(&Os[d][ch * 8]);
      }
    }
  }
  Ps[a][dl] = sum;
  __syncthreads();
  if (t < 64) {
    float tot = Ps[0][t] + Ps[1][t] + Ps[2][t] + Ps[3][t];
    inv[d0 + t] = 1.0f / sqrtf(tot);
  }
}

// ---------------- kernel 2: MFMA GEMM + fused dual top-2 ----------------
// grid (96, 8). 128x128 tile, 4 waves, each wave a 64x64 quadrant of 4x4
// 16x16 fragments. Per K-step (32 ch): global_load_lds stages the swizzled
// [128][128B] fp16 tiles directly (no VGPR round-trip, no prefetch regs ->
// no scratch spill, which was R2/R3's 2-4 GB WRITE_SIZE killer).
// 3-term MFMA: acc += Ah*Bh + Ah*Bl + Al*Bh.
// LDS 41 KB + ~135 VGPR -> 3 blocks/CU under __launch_bounds__(256,3).
__global__ __launch_bounds__(256, 3)
void sim_top2_mfma() {
  __shared__ unsigned short As[128 * 64];  // 16 KB, linear, swizzled rows
  __shared__ unsigned short Bs[128 * 64];
  __shared__ Top2 rowW[2][128];            // per-wc row partials (persistent)
  __shared__ Top2 colW[2][128];            // per-wr col partials (per j-tile)
  __shared__ float iaS[128];
  __shared__ float ibS[128];

  const int itile = blockIdx.x, slice = blockIdx.y;
  const int i0 = itile * 128;
  const int tid = threadIdx.x;
  const int wave = tid >> 6, lane = tid & 63;
  const int wr = wave >> 1, wc = wave & 1;
  const int fr = lane & 15, kq = lane >> 4;

  if (tid < 128) {
    iaS[tid] = g_invA[i0 + tid];
    Top2 z; z.v0 = -1e30f; z.v1 = -1e30f; z.i0 = 0x7fffffff; z.i1 = 0x7fffffff;
    rowW[0][tid] = z; rowW[1][tid] = z;
  }

  // staging addresses: wave w copies rows w*32+it*8+(lane>>3), chunk lane&7
  const char* gAl = (const char*)g_AT
      + (size_t)(i0 + wave * 32 + (lane >> 3)) * 2048 + (lane & 7) * 16;
  char* const ldsA0 = (char*)As + wave * 4096;
  char* const ldsB0 = (char*)Bs + wave * 4096;

  // loop-invariant LDS fragment byte offsets (logical chunk ^ (row&7))
  const int f7 = fr & 7;
  const int cHi = (kq ^ f7) << 4;
  const int cLo = ((kq + 4) ^ f7) << 4;
  int aOff[4], bOff[4];
#pragma unroll
  for (int mi = 0; mi < 4; ++mi) aOff[mi] = (wr * 64 + mi * 16 + fr) * 128;
#pragma unroll
  for (int ni = 0; ni < 4; ++ni) bOff[ni] = (wc * 64 + ni * 16 + fr) * 128;

  for (int jt = slice * JT_PER_S; jt < slice * JT_PER_S + JT_PER_S; ++jt) {
    const int j0 = jt * 128;
    if (tid < 128) ibS[tid] = g_invB[j0 + tid];

    f32x4 acc[4][4];
#pragma unroll
    for (int mi = 0; mi < 4; ++mi)
#pragma unroll
      for (int ni = 0; ni < 4; ++ni)
#pragma unroll
        for (int q = 0; q < 4; ++q) acc[mi][ni][q] = 0.f;

    const char* gBl = (const char*)g_BT
        + (size_t)(j0 + wave * 32 + (lane >> 3)) * 2048 + (lane & 7) * 16;

    for (int g = 0; g < 16; ++g) {
      __syncthreads();                     // previous tile fully consumed
#pragma unroll
      for (int it = 0; it < 4; ++it) {
        gload16(gAl + (size_t)it * 8 * 2048 + (size_t)g * 128, ldsA0 + it * 1024);
        gload16(gBl + (size_t)it * 8 * 2048 + (size_t)g * 128, ldsB0 + it * 1024);
      }
      __syncthreads();                     // vmcnt(0) drain + barrier: tile ready

      f16x8 ah[4], al[4];
#pragma unroll
      for (int mi = 0; mi < 4; ++mi) {
        ah[mi] = *reinterpret_cast<const f16x8*>((const char*)As + aOff[mi] + cHi);
        al[mi] = *reinterpret_cast<const f16x8*>((const char*)As + aOff[mi] + cLo);
      }
#pragma unroll
      for (int ni = 0; ni < 4; ++ni) {
        f16x8 bh = *reinterpret_cast<const f16x8*>((const char*)Bs + bOff[ni] + cHi);
        f16x8 bl = *reinterpret_cast<const f16x8*>((const char*)Bs + bOff[ni] + cLo);
#pragma unroll
        for (int mi = 0; mi < 4; ++mi) {
          acc[mi][ni] = __builtin_amdgcn_mfma_f32_16x16x32_f16(ah[mi], bh, acc[mi][ni], 0, 0, 0);
          acc[mi][ni] = __builtin_amdgcn_mfma_f32_16x16x32_f16(ah[mi], bl, acc[mi][ni], 0, 0, 0);
          acc[mi][ni] = __builtin_amdgcn_mfma_f32_16x16x32_f16(al[mi], bh, acc[mi][ni], 0, 0, 0);
        }
      }
    }

    // ---- epilogue: scale to cosine sims (C layout: col=fr, row=kq*4+r) ----
    float ib[4];
#pragma unroll
    for (int ni = 0; ni < 4; ++ni) ib[ni] = ibS[wc * 64 + ni * 16 + fr];
#pragma unroll
    for (int mi = 0; mi < 4; ++mi)
#pragma unroll
      for (int r = 0; r < 4; ++r) {
        const float iar = iaS[wr * 64 + mi * 16 + kq * 4 + r];
#pragma unroll
        for (int ni = 0; ni < 4; ++ni)
          acc[mi][ni][r] *= iar * ib[ni];
      }

    // ---- row top-2 (reduce over cols: lanes sharing kq, then ni) ----
#pragma unroll
    for (int mi = 0; mi < 4; ++mi) {
#pragma unroll
      for (int r = 0; r < 4; ++r) {
        const int row = wr * 64 + mi * 16 + kq * 4 + r;
        float v0 = -1e30f, v1 = -1e30f; int id0 = 0x7fffffff, id1 = 0x7fffffff;
#pragma unroll
        for (int ni = 0; ni < 4; ++ni)
          t2_ins(acc[mi][ni][r], j0 + wc * 64 + ni * 16 + fr, v0, id0, v1, id1);
#pragma unroll
        for (int m = 1; m < 16; m <<= 1) {
          float ov0 = __shfl_xor(v0, m), ov1 = __shfl_xor(v1, m);
          int oi0 = __shfl_xor(id0, m), oi1 = __shfl_xor(id1, m);
          t2_ins(ov0, oi0, v0, id0, v1, id1);
          t2_ins(ov1, oi1, v0, id0, v1, id1);
        }
        if (fr == 0) {                     // unique (wave, kq, mi, r) owner
          Top2 tT = rowW[wc][row];
          t2_ins(v0, id0, tT.v0, tT.i0, tT.v1, tT.i1);
          t2_ins(v1, id1, tT.v0, tT.i0, tT.v1, tT.i1);
          rowW[wc][row] = tT;
        }
      }
    }

    // ---- col top-2 (reduce 16 in-thread rows, then across kq groups) ----
#pragma unroll
    for (int ni = 0; ni < 4; ++ni) {
      float v0 = -1e30f, v1 = -1e30f; int id0 = 0x7fffffff, id1 = 0x7fffffff;
#pragma unroll
      for (int mi = 0; mi < 4; ++mi)
#pragma unroll
        for (int r = 0; r < 4; ++r)
          t2_ins(acc[mi][ni][r], i0 + wr * 64 + mi * 16 + kq * 4 + r, v0, id0, v1, id1);
#pragma unroll
      for (int m = 16; m < 64; m <<= 1) {
        float ov0 = __shfl_xor(v0, m), ov1 = __shfl_xor(v1, m);
        int oi0 = __shfl_xor(id0, m), oi1 = __shfl_xor(id1, m);
        t2_ins(ov0, oi0, v0, id0, v1, id1);
        t2_ins(ov1, oi1, v0, id0, v1, id1);
      }
      if (kq == 0) {
        Top2 tT; tT.v0 = v0; tT.v1 = v1; tT.i0 = id0; tT.i1 = id1;
        colW[wr][wc * 64 + ni * 16 + fr] = tT;
      }
    }
    __syncthreads();
    if (tid < 128) {
      Top2 tT = colW[0][tid];
      Top2 o  = colW[1][tid];
      t2_ins(o.v0, o.i0, tT.v0, tT.i0, tT.v1, tT.i1);
      t2_ins(o.v1, o.i1, tT.v0, tT.i0, tT.v1, tT.i1);
      g_cpart[itile][j0 + tid] = tT;
    }
  }

  __syncthreads();
  if (tid < 128) {
    Top2 tT = rowW[0][tid];
    Top2 o  = rowW[1][tid];
    t2_ins(o.v0, o.i0, tT.v0, tT.i0, tT.v1, tT.i1);
    t2_ins(o.v1, o.i1, tT.v0, tT.i0, tT.v1, tT.i1);
    g_rpart[slice][i0 + tid] = tT;
  }
}

// ---------------- kernel 3: merge partials ----------------
__global__ void merge_kernel() {
  int i = blockIdx.x * 256 + threadIdx.x;
  if (i >= N) return;
  {
    float v0 = -1e30f, v1 = -1e30f; int id0 = 0x7fffffff, id1 = 0x7fffffff;
#pragma unroll
    for (int s = 0; s < NS; ++s) {
      Top2 p = g_rpart[s][i];
      t2_ins(p.v0, p.i0, v0, id0, v1, id1);
      t2_ins(p.v1, p.i1, v0, id0, v1, id1);
    }
    float d0 = 2.f - 2.f * v0, d1 = 2.f - 2.f * v1;
    g_nn12[i] = id0; g_r12[i] = d0 / (d1 + 1e-8f); g_sim0[i] = v0;
  }
  {
    float v0 = -1e30f, v1 = -1e30f; int id0 = 0x7fffffff, id1 = 0x7fffffff;
    for (int it = 0; it < NTILE; ++it) {
      Top2 p = g_cpart[it][i];
      t2_ins(p.v0, p.i0, v0, id0, v1, id1);
      t2_ins(p.v1, p.i1, v0, id0, v1, id1);
    }
    float d0 = 2.f - 2.f * v0, d1 = 2.f - 2.f * v1;
    g_nn21[i] = id0; g_r21[i] = d0 / (d1 + 1e-8f);
  }
}

// ---------------- kernel 4: mutual-NN + ratio mask, outputs ----------------
__global__ void finalize_kernel(float* __restrict__ out) {
  int i = blockIdx.x * 256 + threadIdx.x;
  if (i >= N) return;
  int j = g_nn12[i];
  int jc = j < 0 ? 0 : (j >= N ? N - 1 : j);
  bool mask = (g_nn21[jc] == i) && (g_r12[i] <= 0.95f) && (g_r21[jc] <= 0.95f);
  out[i]         = bf16_quant(mask ? g_sim0[i] : 0.f);
  out[N + i]     = bf16_quant((float)j);
  out[2 * N + i] = mask ? 1.f : 0.f;
}

extern "C" void kernel_launch(void* const* d_in, const int* in_sizes, int n_in,
                              void* d_out, int out_size, void* d_ws, size_t ws_size,
                              hipStream_t stream) {
  const float* A = (const float*)d_in[0];  // fp32, channel-major [CH][N]
  const float* B = (const float*)d_in[1];
  (void)d_ws; (void)ws_size;

  prep_kernel<<<dim3(192, 2), 256, 0, stream>>>(A, B);
  sim_top2_mfma<<<dim3(NTILE, NS), 256, 0, stream>>>();
  merge_kernel<<<dim3((N + 255) / 256), 256, 0, stream>>>();
  finalize_kernel<<<dim3((N + 255) / 256), 256, 0, stream>>>((float*)d_out);
}